// Round 6
// baseline (219.573 us; speedup 1.0000x reference)
//
#include <hip/hip_runtime.h>
#include <math.h>

// LRML distance-embedding head:
//   ue = renorm(user_emb[uid]); ie = renorm(item_emb[iid])       (max_norm=1)
//   scores = softmax((ue*ie) @ W_att^T)   [M=10]
//   rel    = scores @ memory              [D=32]
//   out    = -||ue + rel - ie||^2
//
// Layout: 32 lanes per batch element (1 float per lane of the D=32 row).
// B=16384 -> 2048 blocks -> 8 blocks/CU -> 32 waves/CU. Each row gather is
// one coalesced 128-B request (32 lanes x 4 B). No LDS, no barrier: weights
// (2 x 1280 B, L1-resident after warmup) load straight to registers; waves
// are fully decoupled.
//
// Register-pressure hardening:
//  - __launch_bounds__(BLOCK, 8): pin allocator under the 64-VGPR cliff so
//    the max-occupancy rationale cannot be silently undone.
//  - memory-matrix loads (mreg) issued AFTER the score reduce, not up front:
//    they are consumed only after softmax, so the deferred issue overlaps
//    their L1-hit latency with softmax VALU work and cuts ~10 live VGPRs at
//    the peak (gather chain + W_att only).
//
// NOTE: frozen at the Round-5 structure. Five consecutive broker timeouts
// mean every revision since the 215.6 us baseline is unmeasured; further
// blind mutation adds risk without information. First successful profile
// must arbitrate: top-k dispatch split, VGPR_Count, FETCH_SIZE, dur_us.

#define D 32
#define M 10
#define BLOCK 256
#define LANES_PER_ELEM 32

__global__ __launch_bounds__(BLOCK, 8) void lrml_kernel(
    const int* __restrict__ user_ids,
    const int* __restrict__ item_ids,
    const float* __restrict__ user_emb,
    const float* __restrict__ item_emb,
    const float* __restrict__ W_att,
    const float* __restrict__ memory,
    float* __restrict__ out,
    int B)
{
    int gthread = blockIdx.x * BLOCK + threadIdx.x;
    int elem = gthread >> 5;            // batch element
    int g    = gthread & 31;            // float index within the D=32 row
    if (elem >= B) return;              // no barrier -> early return is legal

    // --- issue the long-latency random gather chain FIRST ---
    int uid = user_ids[elem];           // 32-way broadcast load
    int iid = item_ids[elem];
    float ue = user_emb[(size_t)uid * D + g];   // coalesced 128-B row
    float ie = item_emb[(size_t)iid * D + g];

    // --- W_att loads: needed right after the first reduce; issue now so they
    //     fly alongside the gathers ---
    float wreg[M];
    #pragma unroll
    for (int m = 0; m < M; m++)
        wreg[m] = W_att[m * D + g];

    // --- renorm to max L2 norm 1 ---
    float un2 = ue * ue;
    float in2 = ie * ie;
    #pragma unroll
    for (int mask = 1; mask < LANES_PER_ELEM; mask <<= 1) {
        un2 += __shfl_xor(un2, mask, 64);
        in2 += __shfl_xor(in2, mask, 64);
    }
    float su = 1.0f / fmaxf(sqrtf(un2), 1.0f);
    float si = 1.0f / fmaxf(sqrtf(in2), 1.0f);
    ue *= su;
    ie *= si;

    float joint = ue * ie;

    // --- attention scores: (joint @ W_att^T), partial per lane then reduce ---
    float s[M];
    #pragma unroll
    for (int m = 0; m < M; m++)
        s[m] = joint * wreg[m];
    #pragma unroll
    for (int mask = 1; mask < LANES_PER_ELEM; mask <<= 1) {
        #pragma unroll
        for (int m = 0; m < M; m++)
            s[m] += __shfl_xor(s[m], mask, 64);
    }

    // --- memory-matrix loads: consumed after softmax; issue here so L1-hit
    //     latency overlaps the softmax VALU work ---
    float mreg[M];
    #pragma unroll
    for (int m = 0; m < M; m++)
        mreg[m] = memory[m * D + g];

    // --- softmax over M=10 (redundant per lane, all in registers) ---
    float mx = s[0];
    #pragma unroll
    for (int m = 1; m < M; m++) mx = fmaxf(mx, s[m]);
    float sum = 0.0f;
    #pragma unroll
    for (int m = 0; m < M; m++) {
        s[m] = __expf(s[m] - mx);
        sum += s[m];
    }
    float inv = 1.0f / sum;

    // --- rel = scores @ memory (this lane's single float of D) ---
    float rel = 0.0f;
    #pragma unroll
    for (int m = 0; m < M; m++)
        rel += (s[m] * inv) * mreg[m];

    // --- dist = ||ue + rel - ie||^2, reduce across the 32-lane group ---
    float dd = ue + rel - ie;
    float dist = dd * dd;
    #pragma unroll
    for (int mask = 1; mask < LANES_PER_ELEM; mask <<= 1)
        dist += __shfl_xor(dist, mask, 64);

    if (g == 0) out[elem] = -dist;
}

extern "C" void kernel_launch(void* const* d_in, const int* in_sizes, int n_in,
                              void* d_out, int out_size, void* d_ws, size_t ws_size,
                              hipStream_t stream) {
    const int*   user_ids = (const int*)d_in[0];
    const int*   item_ids = (const int*)d_in[1];
    const float* user_emb = (const float*)d_in[2];
    const float* item_emb = (const float*)d_in[3];
    const float* W_att    = (const float*)d_in[4];
    const float* memory   = (const float*)d_in[5];
    float* out = (float*)d_out;

    int B = in_sizes[0];
    int threads = B * LANES_PER_ELEM;
    int grid = (threads + BLOCK - 1) / BLOCK;

    lrml_kernel<<<grid, BLOCK, 0, stream>>>(
        user_ids, item_ids, user_emb, item_emb, W_att, memory, out, B);
}